// Round 13
// baseline (90.469 us; speedup 1.0000x reference)
//
#include <hip/hip_runtime.h>

// GCN layer: out = relu( segment_sum( (h@W * norm)[src], dst ) * norm + b )
//
// Pipeline (de-fused — fusion tested 3x, always neutral/negative):
//   K0 wconv        : Wtg = bf16(W) in MFMA B-fragment order; zero gcur[]  (~2us)
//   K1 gemm_mfma    : scaledh = bf16((h@W)*norm) via mfma_f32_16x16x32_bf16 (~15us)
//   K2 bin_edges    : bin edges by dst>>6, 1024 thr x 8 edges; LDS rank +
//                     1 global atomic per (block,bucket) reservation (~18us)
//   K3 bucket_reduce: per-bucket LDS counting sort + group-owns-node gather,
//                     8 lanes/edge (uint4 = 8 bf16/lane -> 1 instr = 8 edges),
//                     exact-quad fast loop (no masks), padded sorted[] tails,
//                     fused *norm+b, relu 2xfloat4 store.

typedef unsigned int u32;
typedef unsigned short u16;
typedef __attribute__((ext_vector_type(8))) short s16x8;   // 8 bf16 = 4 VGPR
typedef __attribute__((ext_vector_type(4))) float f32x4;

#define NB_LOG 6
#define NPB 64             // nodes per bucket
#define CAP 2048           // edge capacity per bucket (mean ~1024, sd ~32)
#define MAXB 2048          // max buckets supported (N <= 131072)
#define EPB 8192           // edges per bin block (1024 thr x 8)
#define RT 256             // bucket_reduce threads (4 waves)

__device__ __forceinline__ float bf2f(u16 v) {
  return __uint_as_float(((u32)v) << 16);
}
__device__ __forceinline__ u16 f2bf(float f) {
  u32 u = __float_as_uint(f);
  return (u16)((u + 0x7fffu + ((u >> 16) & 1u)) >> 16);  // RNE
}
// accumulate 8 bf16 channels (one uint4) into two float4
__device__ __forceinline__ void acc_bf16x8(float4& lo, float4& hi, uint4 v) {
  lo.x += __uint_as_float(v.x << 16);
  lo.y += __uint_as_float(v.x & 0xFFFF0000u);
  lo.z += __uint_as_float(v.y << 16);
  lo.w += __uint_as_float(v.y & 0xFFFF0000u);
  hi.x += __uint_as_float(v.z << 16);
  hi.y += __uint_as_float(v.z & 0xFFFF0000u);
  hi.z += __uint_as_float(v.w << 16);
  hi.w += __uint_as_float(v.w & 0xFFFF0000u);
}

// ---- K0: W -> bf16 in B-fragment order; zero gcur ----
__global__ __launch_bounds__(256) void wconv(
    const float* __restrict__ W, u16* __restrict__ Wtg, u32* __restrict__ gcur) {
  int o = blockIdx.x * 256 + threadIdx.x;  // 0..8191
  int j = o & 7, col = (o >> 3) & 15, kq = (o >> 7) & 3, ks = (o >> 9) & 3,
      ct = (o >> 11) & 3;
  int k = ks * 32 + kq * 8 + j;
  int n = ct * 16 + col;
  Wtg[o] = f2bf(W[k * 64 + n]);
  if (o < MAXB) gcur[o] = 0;
}

// ---- K1: MFMA GEMM, 64 rows/block (4 waves x 16 rows), 64 cols ----
__global__ __launch_bounds__(256) void gemm_mfma(
    const float* __restrict__ h, const float* __restrict__ norm,
    const u16* __restrict__ Wtg, u16* __restrict__ scaledh, int N) {
  int lane = threadIdx.x & 63, wid = threadIdx.x >> 6;
  int col = lane & 15, kq = lane >> 4;

  s16x8 bfrag[4][4];
#pragma unroll
  for (int ct = 0; ct < 4; ++ct)
#pragma unroll
    for (int ks = 0; ks < 4; ++ks) {
      int f = ct * 16 + ks * 4 + kq;
      bfrag[ct][ks] =
          *reinterpret_cast<const s16x8*>(Wtg + ((size_t)(f * 16 + col) * 8));
    }

  int row0 = blockIdx.x * 64 + wid * 16;
  int myrow = row0 + col;
  int ldrow = myrow < N ? myrow : (N - 1);
  const float* __restrict__ hrow = h + (size_t)ldrow * 128 + kq * 8;

  f32x4 acc[4];
#pragma unroll
  for (int ct = 0; ct < 4; ++ct) acc[ct] = (f32x4){0.f, 0.f, 0.f, 0.f};

#pragma unroll
  for (int ks = 0; ks < 4; ++ks) {
    float4 x0 = *reinterpret_cast<const float4*>(hrow + ks * 32);
    float4 x1 = *reinterpret_cast<const float4*>(hrow + ks * 32 + 4);
    s16x8 a;
    a[0] = (short)f2bf(x0.x); a[1] = (short)f2bf(x0.y);
    a[2] = (short)f2bf(x0.z); a[3] = (short)f2bf(x0.w);
    a[4] = (short)f2bf(x1.x); a[5] = (short)f2bf(x1.y);
    a[6] = (short)f2bf(x1.z); a[7] = (short)f2bf(x1.w);
#pragma unroll
    for (int ct = 0; ct < 4; ++ct)
      acc[ct] =
          __builtin_amdgcn_mfma_f32_16x16x32_bf16(a, bfrag[ct][ks], acc[ct], 0, 0, 0);
  }

#pragma unroll
  for (int reg = 0; reg < 4; ++reg) {
    int node = row0 + kq * 4 + reg;
    if (node < N) {
      float nm = norm[node];
#pragma unroll
      for (int ct = 0; ct < 4; ++ct)
        scaledh[(size_t)node * 64 + ct * 16 + col] = f2bf(acc[ct][reg] * nm);
    }
  }
}

// ---- K2: bin edges by dst>>6 (1024 threads, 8 edges each) ----
__global__ __launch_bounds__(1024) void bin_edges(
    const int* __restrict__ src, const int* __restrict__ dst,
    u32* __restrict__ gcur, u32* __restrict__ bins, int E) {
  __shared__ u32 lhist[MAXB];
  __shared__ u32 lbase[MAXB];
  int t = threadIdx.x;
  for (int i = t; i < MAXB; i += 1024) lhist[i] = 0;
  __syncthreads();
  int e0 = blockIdx.x * EPB;
  int s[8], d[8];
  u32 r[8];
#pragma unroll
  for (int k = 0; k < 8; ++k) {
    int e = e0 + k * 1024 + t;  // coalesced
    bool ok = e < E;
    s[k] = ok ? src[e] : 0;
    d[k] = ok ? dst[e] : -1;
  }
#pragma unroll
  for (int k = 0; k < 8; ++k) {
    if (d[k] >= 0) r[k] = atomicAdd(&lhist[d[k] >> NB_LOG], 1u);  // ds_add_rtn
  }
  __syncthreads();
  for (int i = t; i < MAXB; i += 1024) {
    u32 c = lhist[i];
    lbase[i] = c ? atomicAdd(&gcur[i], c) : 0u;  // 1 global atomic/(block,bucket)
  }
  __syncthreads();
#pragma unroll
  for (int k = 0; k < 8; ++k) {
    if (d[k] >= 0) {
      int bk = d[k] >> NB_LOG;
      u32 p = lbase[bk] + r[k];
      if (p < CAP)
        bins[(size_t)bk * CAP + p] = ((u32)s[k] << NB_LOG) | (u32)(d[k] & (NPB - 1));
    }
  }
}

// ---- K3: counting sort + 8-lanes/edge gather (uint4, exact-quad fast path) ----
__global__ __launch_bounds__(RT) void bucket_reduce(
    const u16* __restrict__ scaledh, const u32* __restrict__ bins,
    const u32* __restrict__ gcur, const float* __restrict__ norm,
    const float* __restrict__ bias, float* __restrict__ out, int N) {
  __shared__ u32 hist[NPB];
  __shared__ u32 startp[NPB + 1];
  __shared__ u32 sorted[CAP + 4];  // +4 zero pad: tail reads need no clamp
  int bkt = blockIdx.x;
  int t = threadIdx.x, lane = t & 63, wid = t >> 6;
  int cnt = (int)gcur[bkt];
  if (cnt > CAP) cnt = CAP;
  if (t < NPB) hist[t] = 0;
  __syncthreads();

  const u32* __restrict__ my = bins + (size_t)bkt * CAP;
  u32 w[CAP / RT];
  u32 rk[CAP / RT];
#pragma unroll
  for (int k = 0; k < CAP / RT; ++k) {
    int e = k * RT + t;  // coalesced
    w[k] = (e < cnt) ? my[e] : 0xFFFFFFFFu;
  }
#pragma unroll
  for (int k = 0; k < CAP / RT; ++k) {
    if (w[k] != 0xFFFFFFFFu)
      rk[k] = atomicAdd(&hist[w[k] & (NPB - 1)], 1u);  // native int LDS atomic
  }
  __syncthreads();
  // wave-level exclusive scan of hist[0..63] (wave 0)
  if (t < NPB) {
    u32 v = hist[t];
    u32 inc = v;
#pragma unroll
    for (int m = 1; m < NPB; m <<= 1) {
      u32 x = __shfl_up(inc, m);
      if (t >= m) inc += x;
    }
    startp[t] = inc - v;
    if (t == NPB - 1) startp[NPB] = inc;
  }
  __syncthreads();
#pragma unroll
  for (int k = 0; k < CAP / RT; ++k) {
    if (w[k] != 0xFFFFFFFFu)
      sorted[startp[w[k] & (NPB - 1)] + rk[k]] = w[k] >> NB_LOG;
  }
  if (t < 4) sorted[cnt + t] = 0;  // pad (indices cnt..cnt+3 valid, point at row 0)
  __syncthreads();

  // Gather: 8-lane group owns one node; one uint4 load instr = 8 edges (8 groups).
  // A/B node-set interleave + 4-edge unroll -> 8 uint4 loads (8KB) in flight.
  int grp = lane >> 3, c8 = lane & 7;
  float4 bl0 = *reinterpret_cast<const float4*>(bias + c8 * 8);
  float4 bl1 = *reinterpret_cast<const float4*>(bias + c8 * 8 + 4);
  int base = bkt << NB_LOG;
  const u16* __restrict__ sh = scaledh + (c8 << 3);

  int rA = (wid << 4) + grp;  // wave covers 16 nodes: wid*16 + {0..7 | 8..15}
  int rB = rA + 8;
  int jA = (int)startp[rA], eA = (int)startp[rA + 1];
  int jB = (int)startp[rB], eB = (int)startp[rB + 1];
  float4 aA0l = {0,0,0,0}, aA0h = {0,0,0,0}, aA1l = {0,0,0,0}, aA1h = {0,0,0,0};
  float4 aB0l = {0,0,0,0}, aB0h = {0,0,0,0}, aB1l = {0,0,0,0}, aB1h = {0,0,0,0};

  // fast path: both lists have full quads — no masks, no clamps
  while (jA + 4 <= eA && jB + 4 <= eB) {
    int iA0 = (int)sorted[jA], iA1 = (int)sorted[jA + 1],
        iA2 = (int)sorted[jA + 2], iA3 = (int)sorted[jA + 3];
    int iB0 = (int)sorted[jB], iB1 = (int)sorted[jB + 1],
        iB2 = (int)sorted[jB + 2], iB3 = (int)sorted[jB + 3];
    uint4 vA0 = *reinterpret_cast<const uint4*>(sh + ((size_t)iA0 << 6));
    uint4 vA1 = *reinterpret_cast<const uint4*>(sh + ((size_t)iA1 << 6));
    uint4 vA2 = *reinterpret_cast<const uint4*>(sh + ((size_t)iA2 << 6));
    uint4 vA3 = *reinterpret_cast<const uint4*>(sh + ((size_t)iA3 << 6));
    uint4 vB0 = *reinterpret_cast<const uint4*>(sh + ((size_t)iB0 << 6));
    uint4 vB1 = *reinterpret_cast<const uint4*>(sh + ((size_t)iB1 << 6));
    uint4 vB2 = *reinterpret_cast<const uint4*>(sh + ((size_t)iB2 << 6));
    uint4 vB3 = *reinterpret_cast<const uint4*>(sh + ((size_t)iB3 << 6));
    acc_bf16x8(aA0l, aA0h, vA0);
    acc_bf16x8(aA1l, aA1h, vA1);
    acc_bf16x8(aA0l, aA0h, vA2);
    acc_bf16x8(aA1l, aA1h, vA3);
    acc_bf16x8(aB0l, aB0h, vB0);
    acc_bf16x8(aB1l, aB1h, vB1);
    acc_bf16x8(aB0l, aB0h, vB2);
    acc_bf16x8(aB1l, aB1h, vB3);
    jA += 4;
    jB += 4;
  }
  // leftover quads, one list at a time
  while (jA + 4 <= eA) {
    int i0 = (int)sorted[jA], i1 = (int)sorted[jA + 1],
        i2 = (int)sorted[jA + 2], i3 = (int)sorted[jA + 3];
    uint4 v0 = *reinterpret_cast<const uint4*>(sh + ((size_t)i0 << 6));
    uint4 v1 = *reinterpret_cast<const uint4*>(sh + ((size_t)i1 << 6));
    uint4 v2 = *reinterpret_cast<const uint4*>(sh + ((size_t)i2 << 6));
    uint4 v3 = *reinterpret_cast<const uint4*>(sh + ((size_t)i3 << 6));
    acc_bf16x8(aA0l, aA0h, v0);
    acc_bf16x8(aA1l, aA1h, v1);
    acc_bf16x8(aA0l, aA0h, v2);
    acc_bf16x8(aA1l, aA1h, v3);
    jA += 4;
  }
  while (jB + 4 <= eB) {
    int i0 = (int)sorted[jB], i1 = (int)sorted[jB + 1],
        i2 = (int)sorted[jB + 2], i3 = (int)sorted[jB + 3];
    uint4 v0 = *reinterpret_cast<const uint4*>(sh + ((size_t)i0 << 6));
    uint4 v1 = *reinterpret_cast<const uint4*>(sh + ((size_t)i1 << 6));
    uint4 v2 = *reinterpret_cast<const uint4*>(sh + ((size_t)i2 << 6));
    uint4 v3 = *reinterpret_cast<const uint4*>(sh + ((size_t)i3 << 6));
    acc_bf16x8(aB0l, aB0h, v0);
    acc_bf16x8(aB1l, aB1h, v1);
    acc_bf16x8(aB0l, aB0h, v2);
    acc_bf16x8(aB1l, aB1h, v3);
    jB += 4;
  }
  // tails (<=3 per list); pad makes the speculative index reads safe
  if (jA < eA || jB < eB) {
    int iA0 = (int)sorted[jA], iA1 = (int)sorted[jA + 1], iA2 = (int)sorted[jA + 2];
    int iB0 = (int)sorted[jB], iB1 = (int)sorted[jB + 1], iB2 = (int)sorted[jB + 2];
    uint4 vA0 = *reinterpret_cast<const uint4*>(sh + ((size_t)iA0 << 6));
    uint4 vA1 = *reinterpret_cast<const uint4*>(sh + ((size_t)iA1 << 6));
    uint4 vA2 = *reinterpret_cast<const uint4*>(sh + ((size_t)iA2 << 6));
    uint4 vB0 = *reinterpret_cast<const uint4*>(sh + ((size_t)iB0 << 6));
    uint4 vB1 = *reinterpret_cast<const uint4*>(sh + ((size_t)iB1 << 6));
    uint4 vB2 = *reinterpret_cast<const uint4*>(sh + ((size_t)iB2 << 6));
    uint4 z = make_uint4(0u, 0u, 0u, 0u);
    vA0 = (jA + 0 < eA) ? vA0 : z;
    vA1 = (jA + 1 < eA) ? vA1 : z;
    vA2 = (jA + 2 < eA) ? vA2 : z;
    vB0 = (jB + 0 < eB) ? vB0 : z;
    vB1 = (jB + 1 < eB) ? vB1 : z;
    vB2 = (jB + 2 < eB) ? vB2 : z;
    acc_bf16x8(aA0l, aA0h, vA0);
    acc_bf16x8(aA1l, aA1h, vA1);
    acc_bf16x8(aA0l, aA0h, vA2);
    acc_bf16x8(aB0l, aB0h, vB0);
    acc_bf16x8(aB1l, aB1h, vB1);
    acc_bf16x8(aB0l, aB0h, vB2);
  }

  int nodeA = base + rA, nodeB = base + rB;
  if (nodeA < N) {
    float nm = norm[nodeA];
    float4 o0, o1;
    o0.x = fmaxf(fmaf(aA0l.x + aA1l.x, nm, bl0.x), 0.f);
    o0.y = fmaxf(fmaf(aA0l.y + aA1l.y, nm, bl0.y), 0.f);
    o0.z = fmaxf(fmaf(aA0l.z + aA1l.z, nm, bl0.z), 0.f);
    o0.w = fmaxf(fmaf(aA0l.w + aA1l.w, nm, bl0.w), 0.f);
    o1.x = fmaxf(fmaf(aA0h.x + aA1h.x, nm, bl1.x), 0.f);
    o1.y = fmaxf(fmaf(aA0h.y + aA1h.y, nm, bl1.y), 0.f);
    o1.z = fmaxf(fmaf(aA0h.z + aA1h.z, nm, bl1.z), 0.f);
    o1.w = fmaxf(fmaf(aA0h.w + aA1h.w, nm, bl1.w), 0.f);
    float* op = out + (size_t)nodeA * 64 + c8 * 8;
    *reinterpret_cast<float4*>(op) = o0;
    *reinterpret_cast<float4*>(op + 4) = o1;
  }
  if (nodeB < N) {
    float nm = norm[nodeB];
    float4 o0, o1;
    o0.x = fmaxf(fmaf(aB0l.x + aB1l.x, nm, bl0.x), 0.f);
    o0.y = fmaxf(fmaf(aB0l.y + aB1l.y, nm, bl0.y), 0.f);
    o0.z = fmaxf(fmaf(aB0l.z + aB1l.z, nm, bl0.z), 0.f);
    o0.w = fmaxf(fmaf(aB0l.w + aB1l.w, nm, bl0.w), 0.f);
    o1.x = fmaxf(fmaf(aB0h.x + aB1h.x, nm, bl1.x), 0.f);
    o1.y = fmaxf(fmaf(aB0h.y + aB1h.y, nm, bl1.y), 0.f);
    o1.z = fmaxf(fmaf(aB0h.z + aB1h.z, nm, bl1.z), 0.f);
    o1.w = fmaxf(fmaf(aB0h.w + aB1h.w, nm, bl1.w), 0.f);
    float* op = out + (size_t)nodeB * 64 + c8 * 8;
    *reinterpret_cast<float4*>(op) = o0;
    *reinterpret_cast<float4*>(op + 4) = o1;
  }
}

// ---- fallback (atomic scatter) ----
__global__ __launch_bounds__(256) void zero_out(float4* __restrict__ o4, size_t n4) {
  size_t tid = blockIdx.x * 256 + threadIdx.x;
  size_t stride = (size_t)gridDim.x * 256;
  for (size_t i = tid; i < n4; i += stride) o4[i] = make_float4(0.f, 0.f, 0.f, 0.f);
}

__global__ __launch_bounds__(256) void scatter_edges(
    const u16* __restrict__ scaledh, const int* __restrict__ src,
    const int* __restrict__ dst, float* __restrict__ agg, int E) {
  int lane = threadIdx.x & 63;
  int gwid = (blockIdx.x * 256 + threadIdx.x) >> 6;
  int nw = (gridDim.x * 256) >> 6;
  for (int e = gwid; e < E; e += nw) {
    int s = __builtin_amdgcn_readfirstlane(src[e]);
    int d = __builtin_amdgcn_readfirstlane(dst[e]);
    float v = bf2f(scaledh[(size_t)s * 64 + lane]);
    unsafeAtomicAdd(&agg[(size_t)d * 64 + lane], v);
  }
}

__global__ __launch_bounds__(256) void finalize(
    float4* __restrict__ out4, const float* __restrict__ norm,
    const float4* __restrict__ b4, int N) {
  size_t total4 = (size_t)N * 16;
  size_t tid = blockIdx.x * 256 + threadIdx.x;
  size_t stride = (size_t)gridDim.x * 256;
  for (size_t t = tid; t < total4; t += stride) {
    int i = (int)(t >> 4), q = (int)(t & 15);
    float4 v = out4[t];
    float nm = norm[i];
    float4 bb = b4[q];
    v.x = fmaxf(fmaf(v.x, nm, bb.x), 0.f);
    v.y = fmaxf(fmaf(v.y, nm, bb.y), 0.f);
    v.z = fmaxf(fmaf(v.z, nm, bb.z), 0.f);
    v.w = fmaxf(fmaf(v.w, nm, bb.w), 0.f);
    out4[t] = v;
  }
}

extern "C" void kernel_launch(void* const* d_in, const int* in_sizes, int n_in,
                              void* d_out, int out_size, void* d_ws, size_t ws_size,
                              hipStream_t stream) {
  const float* h    = (const float*)d_in[0];
  const float* norm = (const float*)d_in[1];
  const float* W    = (const float*)d_in[2];
  const float* b    = (const float*)d_in[3];
  const int*   src  = (const int*)d_in[4];
  const int*   dst  = (const int*)d_in[5];

  int N = in_sizes[1];
  int E = in_sizes[4];
  int nbuckets = (N + NPB - 1) >> NB_LOG;
  int nrb = (N + 63) >> 6;
  int nbinb = (E + EPB - 1) / EPB;

  char* ws = (char*)d_ws;
  size_t off = 0;
  u16* scaledh = (u16*)(ws + off); off += (((size_t)N * 64 * 2) + 255) & ~(size_t)255;
  u32* gcur    = (u32*)(ws + off); off += (MAXB * 4 + 255) & ~(size_t)255;
  u16* Wtg     = (u16*)(ws + off); off += (8192 * 2 + 255) & ~(size_t)255;
  u32* bins    = (u32*)(ws + off); off += (size_t)MAXB * CAP * 4;
  size_t needed = off;
  size_t needed_fb = (size_t)((char*)bins - ws);  // fallback: scaledh+gcur+Wtg only

  if (ws_size >= needed && nbuckets <= MAXB) {
    wconv<<<32, 256, 0, stream>>>(W, Wtg, gcur);
    gemm_mfma<<<nrb, 256, 0, stream>>>(h, norm, Wtg, scaledh, N);
    bin_edges<<<nbinb, 1024, 0, stream>>>(src, dst, gcur, bins, E);
    bucket_reduce<<<nbuckets, RT, 0, stream>>>(scaledh, bins, gcur, norm,
                                               b, (float*)d_out, N);
  } else if (ws_size >= needed_fb) {
    float* agg = (float*)d_out;
    wconv<<<32, 256, 0, stream>>>(W, Wtg, gcur);
    gemm_mfma<<<nrb, 256, 0, stream>>>(h, norm, Wtg, scaledh, N);
    zero_out<<<1024, 256, 0, stream>>>((float4*)agg, (size_t)N * 16);
    scatter_edges<<<2048, 256, 0, stream>>>(scaledh, src, dst, agg, E);
    finalize<<<1024, 256, 0, stream>>>((float4*)agg, norm, (const float4*)b, N);
  }
}